// Round 10
// baseline (142.596 us; speedup 1.0000x reference)
//
#include <hip/hip_runtime.h>
#include <hip/hip_bf16.h>

typedef unsigned short u16;
typedef unsigned int u32;
typedef __attribute__((ext_vector_type(8))) short bf16x8;
typedef __attribute__((ext_vector_type(4))) float f32x4;

#define NEXP 8
#define NTOK 4096
#define DDIM 1024
#define MAX_TILES 80

__device__ __forceinline__ u16 f2bf(float f) {
    u32 u = __float_as_uint(f);
    u += 0x7fff + ((u >> 16) & 1);  // RNE
    return (u16)(u >> 16);
}

__device__ __forceinline__ float bf2f(u32 u) { return __uint_as_float(u << 16); }

__device__ __forceinline__ void gload16(const void* g, void* l) {
    __builtin_amdgcn_global_load_lds((const __attribute__((address_space(1))) u32*)g,
                                     (__attribute__((address_space(3))) u32*)l, 16, 0, 0);
}

__device__ __forceinline__ void cvt8(const float* src, u16* dst) {
    float4 a = ((const float4*)src)[0], b = ((const float4*)src)[1];
    uint4 o;
    o.x = (u32)f2bf(a.x) | ((u32)f2bf(a.y) << 16);
    o.y = (u32)f2bf(a.z) | ((u32)f2bf(a.w) << 16);
    o.z = (u32)f2bf(b.x) | ((u32)f2bf(b.y) << 16);
    o.w = (u32)f2bf(b.z) | ((u32)f2bf(b.w) << 16);
    *(uint4*)dst = o;
}

// ---------------- gate (blocks 0..1023) + cvt w1,w3,w2 (blocks 1024..1535) --------------
__global__ __launch_bounds__(256) void gate_cvt_kernel(const float* __restrict__ x,
                                                       const float* __restrict__ gw,
                                                       const float* __restrict__ w1,
                                                       const float* __restrict__ w3,
                                                       const float* __restrict__ w2,
                                                       int* __restrict__ t2i, float* __restrict__ t2w,
                                                       u16* __restrict__ xb, u16* __restrict__ wb) {
    int bid = blockIdx.x;
    int tid = threadIdx.x;
    if (bid >= 1024) {
        // convert w1|w3|w2 -> wb (contiguous bf16), 3.14M chunks of 8 elems
        for (int i = (bid - 1024) * 256 + tid; i < 3145728; i += 131072) {
            const float* src;
            if (i < 1048576)       src = w1 + (size_t)i * 8;
            else if (i < 2097152)  src = w3 + ((size_t)i - 1048576) * 8;
            else                   src = w2 + ((size_t)i - 2097152) * 8;
            cvt8(src, wb + (size_t)i * 8);
        }
        return;
    }
    int wv = tid >> 6, lane = tid & 63;
    int t = bid * 4 + wv;
    const float4* xr = (const float4*)(x + (size_t)t * DDIM);
    float4 xv[4];
#pragma unroll
    for (int q = 0; q < 4; q++) xv[q] = xr[lane * 4 + q];

    uint4 o0, o1;
    o0.x = (u32)f2bf(xv[0].x) | ((u32)f2bf(xv[0].y) << 16);
    o0.y = (u32)f2bf(xv[0].z) | ((u32)f2bf(xv[0].w) << 16);
    o0.z = (u32)f2bf(xv[1].x) | ((u32)f2bf(xv[1].y) << 16);
    o0.w = (u32)f2bf(xv[1].z) | ((u32)f2bf(xv[1].w) << 16);
    o1.x = (u32)f2bf(xv[2].x) | ((u32)f2bf(xv[2].y) << 16);
    o1.y = (u32)f2bf(xv[2].z) | ((u32)f2bf(xv[2].w) << 16);
    o1.z = (u32)f2bf(xv[3].x) | ((u32)f2bf(xv[3].y) << 16);
    o1.w = (u32)f2bf(xv[3].z) | ((u32)f2bf(xv[3].w) << 16);
    uint4* xbo = (uint4*)(xb + (size_t)t * DDIM + lane * 16);
    xbo[0] = o0;
    xbo[1] = o1;

    float acc[NEXP];
#pragma unroll
    for (int e = 0; e < NEXP; e++) acc[e] = 0.f;
#pragma unroll
    for (int e = 0; e < NEXP; e++) {
#pragma unroll
        for (int q = 0; q < 4; q++) {
            float4 g = ((const float4*)gw)[e * 256 + lane * 4 + q];
            acc[e] += xv[q].x * g.x + xv[q].y * g.y + xv[q].z * g.z + xv[q].w * g.w;
        }
    }
#pragma unroll
    for (int e = 0; e < NEXP; e++) {
        float v = acc[e];
#pragma unroll
        for (int off = 32; off; off >>= 1) v += __shfl_xor(v, off, 64);
        acc[e] = v;
    }
    if (lane == 0) {
        float m = acc[0];
#pragma unroll
        for (int e = 1; e < NEXP; e++) m = fmaxf(m, acc[e]);
        float p[NEXP]; float s = 0.f;
#pragma unroll
        for (int e = 0; e < NEXP; e++) { p[e] = __expf(acc[e] - m); s += p[e]; }
        float inv = 1.f / s;
        float best = -1.f, sec = -1.f; int bi = 0, si = 0;
#pragma unroll
        for (int e = 0; e < NEXP; e++) {
            float pe = p[e] * inv;
            if (pe > best) { sec = best; si = bi; best = pe; bi = e; }
            else if (pe > sec) { sec = pe; si = e; }
        }
        t2i[2 * t] = bi;  t2i[2 * t + 1] = si;
        t2w[2 * t] = best; t2w[2 * t + 1] = sec;
    }
}

// ---------------- sort: histogram + block scan + stable counting sort (1 block) --------
// ctl layout (ints): [16..25) slot offsets, [24] total, [25] ntiles,
//   [32..112) tile_expert, [112..192) tile_rowbase, [192..272) tile_segend,
//   [280..289) tilestart prefix (per expert)
__global__ __launch_bounds__(1024) void sort_kernel(const int* __restrict__ t2i,
                                                    const float* __restrict__ t2w,
                                                    int* __restrict__ ctl,
                                                    int* __restrict__ slot_token,
                                                    float* __restrict__ slot_wt,
                                                    int* __restrict__ t2slot) {
    __shared__ int sb[NEXP][1024];  // 32 KB
    __shared__ int wsum[16];
    __shared__ int sex[16];
    __shared__ int stot[NEXP];
    __shared__ int soffs[NEXP + 1];
    int tid = threadIdx.x;
    int lane = tid & 63, wv = tid >> 6;

    int4 a = *(const int4*)(t2i + tid * 8);
    int4 b = *(const int4*)(t2i + tid * 8 + 4);
    int ev0 = a.x, ev1 = a.y, ev2 = a.z, ev3 = a.w;
    int ev4 = b.x, ev5 = b.y, ev6 = b.z, ev7 = b.w;
    u32 cnt = (1u << (ev0 * 4)) + (1u << (ev1 * 4)) + (1u << (ev2 * 4)) + (1u << (ev3 * 4)) +
              (1u << (ev4 * 4)) + (1u << (ev5 * 4)) + (1u << (ev6 * 4)) + (1u << (ev7 * 4));

    for (int e = 0; e < NEXP; e++) {
        int v = (cnt >> (e * 4)) & 15;
        int inc = v;
#pragma unroll
        for (int off = 1; off < 64; off <<= 1) {
            int n = __shfl_up(inc, off, 64);
            if (lane >= off) inc += n;
        }
        if (lane == 63) wsum[wv] = inc;
        __syncthreads();
        if (wv == 0) {
            int w = (lane < 16) ? wsum[lane] : 0;
            int winc = w;
#pragma unroll
            for (int off = 1; off < 16; off <<= 1) {
                int n = __shfl_up(winc, off, 64);
                if (lane >= off) winc += n;
            }
            if (lane < 16) sex[lane] = winc - w;
            if (lane == 15) stot[e] = winc;
        }
        __syncthreads();
        sb[e][tid] = sex[wv] + inc - v;
        __syncthreads();
    }
    if (tid == 0) {
        int o = 0, tt = 0;
        for (int e = 0; e < NEXP; e++) {
            soffs[e] = o;
            ctl[16 + e] = o;
            ctl[280 + e] = tt;  // tilestart prefix
            int n = stot[e];
            for (int r = 0; r < n; r += 128) {
                ctl[32 + tt] = e; ctl[112 + tt] = o + r; ctl[192 + tt] = o + n; tt++;
            }
            o += n;
        }
        soffs[NEXP] = o; ctl[24] = o; ctl[25] = tt; ctl[288] = tt;
    }
    __syncthreads();
#pragma unroll
    for (int j = 0; j < 8; j++) {
        int e;
        switch (j) {
            case 0: e = ev0; break; case 1: e = ev1; break; case 2: e = ev2; break;
            case 3: e = ev3; break; case 4: e = ev4; break; case 5: e = ev5; break;
            case 6: e = ev6; break; default: e = ev7; break;
        }
        int base = sb[e][tid];
        sb[e][tid] = base + 1;
        int slot = soffs[e] + base;
        int p = tid * 8 + j;
        slot_token[slot] = p >> 1;
        slot_wt[slot] = t2w[p];
        t2slot[p] = slot;
    }
}

// ---------------- GEMM0: pure grid, 128x64 dual-B, BK=32, 32KB LDS, 5 blocks/CU ---------
// H=Xg@w1^T, G=Xg@w3^T (dual acc), A=silu(H)*G -> Abuf bf16. R4-exact inner loop.
__global__ __launch_bounds__(256, 5) void gemm0_kernel(
    const u16* __restrict__ Amat, const u16* __restrict__ B1g, const u16* __restrict__ B2g,
    u16* __restrict__ OutB,
    const int* __restrict__ ctl, const int* __restrict__ slot_token) {
    constexpr int NB = 2;
    constexpr int NCB = 16;
    constexpr int NK = 32;

    int bid = blockIdx.x;
    int ntiles = ctl[25];
    int N = ntiles * NCB;
    if (bid >= N) return;
    // bijective XCD swizzle (m204)
    int q = N >> 3, r = N & 7;
    int xcd = bid & 7, seq = bid >> 3;
    int n = (xcd < r ? xcd * (q + 1) : r * (q + 1) + (xcd - r) * q) + seq;
    int e = 0, tstart = 0, tiles_e = 0, m = n;
    for (; e < NEXP; e++) {
        tstart = ctl[280 + e];
        tiles_e = ctl[281 + e] - tstart;
        int sz = tiles_e * NCB;
        if (m < sz) break;
        m -= sz;
    }
    if (e == NEXP) return;
    int cb = m / tiles_e;
    int tt = tstart + (m - cb * tiles_e);
    int rowbase = ctl[112 + tt];
    int segend = ctl[192 + tt];

    __shared__ __align__(16) u16 smem[2 * 128 * 32 + 2 * 64 * 32 + 2 * 64 * 32];
    u16* sA = smem;                  // [2][128][32]
    u16* sB1 = smem + 2 * 128 * 32;  // [2][64][32]
    u16* sB2 = sB1 + 2 * 64 * 32;    // [2][64][32]

    int tid = threadIdx.x;
    int lane = tid & 63;
    int wv = tid >> 6;
    int wrow = wv >> 1, wcol = wv & 1;
    int lr = lane >> 2;
    int cS = (((lane & 3) ^ ((lane >> 3) & 3)) << 3);
    int l15 = lane & 15, hi = lane >> 4;
    int csr = ((hi ^ ((l15 >> 1) & 3)) << 3);

    u32 rowA[2];
#pragma unroll
    for (int i = 0; i < 2; i++) {
        int slot = rowbase + wv * 32 + i * 16 + lr;
        if (slot >= segend) slot = rowbase;
        rowA[i] = (u32)slot_token[slot] * 1024;
    }
    u32 rowB0;
    {
        int rr = cb * 64 + wv * 16 + lr;
        rowB0 = (u32)e * 1048576 + (u32)rr * 1024;
    }

    f32x4 accH[4][NB], accG[4][NB];
    f32x4 zero = {0.f, 0.f, 0.f, 0.f};
#pragma unroll
    for (int m2 = 0; m2 < 4; m2++)
#pragma unroll
        for (int nn = 0; nn < NB; nn++) { accH[m2][nn] = zero; accG[m2][nn] = zero; }

    auto stage = [&](int buf, int kt) {
        int k0 = kt * 32 + cS;
        gload16(Amat + rowA[0] + k0, sA + buf * 4096 + (wv * 32) * 32);
        gload16(Amat + rowA[1] + k0, sA + buf * 4096 + (wv * 32 + 16) * 32);
        gload16(B1g + rowB0 + k0, sB1 + buf * 2048 + (wv * 16) * 32);
        gload16(B2g + rowB0 + k0, sB2 + buf * 2048 + (wv * 16) * 32);
    };

    auto compute = [&](int buf) {
        bf16x8 av[4];
#pragma unroll
        for (int m2 = 0; m2 < 4; m2++) {
            int rr = wrow * 64 + m2 * 16 + l15;
            av[m2] = *(const bf16x8*)(sA + buf * 4096 + rr * 32 + csr);
        }
        bf16x8 b1v[NB], b2v[NB];
#pragma unroll
        for (int nn = 0; nn < NB; nn++) {
            int rr = wcol * 32 + nn * 16 + l15;
            b1v[nn] = *(const bf16x8*)(sB1 + buf * 2048 + rr * 32 + csr);
            b2v[nn] = *(const bf16x8*)(sB2 + buf * 2048 + rr * 32 + csr);
        }
#pragma unroll
        for (int m2 = 0; m2 < 4; m2++)
#pragma unroll
            for (int nn = 0; nn < NB; nn++) {
                accH[m2][nn] = __builtin_amdgcn_mfma_f32_16x16x32_bf16(av[m2], b1v[nn], accH[m2][nn], 0, 0, 0);
                accG[m2][nn] = __builtin_amdgcn_mfma_f32_16x16x32_bf16(av[m2], b2v[nn], accG[m2][nn], 0, 0, 0);
            }
    };

    stage(0, 0);
    for (int kt = 0; kt < NK; ++kt) {
        __syncthreads();
        if (kt + 1 < NK) stage((kt + 1) & 1, kt + 1);
        compute(kt & 1);
    }

    int colblock = cb * 64 + wcol * 32;
#pragma unroll
    for (int m2 = 0; m2 < 4; m2++) {
        int slotbase = rowbase + wrow * 64 + m2 * 16 + hi * 4;
#pragma unroll
        for (int nn = 0; nn < NB; nn++) {
            int col = colblock + nn * 16 + l15;
#pragma unroll
            for (int j = 0; j < 4; j++) {
                int slot = slotbase + j;
                if (slot < segend) {
                    float h = accH[m2][nn][j], g = accG[m2][nn][j];
                    float aa = (h / (1.f + __expf(-h))) * g;  // silu(h)*g
                    OutB[(size_t)slot * 1024 + col] = f2bf(aa);
                }
            }
        }
    }
}

// ---------------- GEMM1: Y2[slot] = Abuf @ w2^T (bf16 out, plain stores) ----------------
// 128x128, BK=32, 32KB LDS, 512-block grid (grid-capped at 2/CU).
__global__ __launch_bounds__(256, 4) void gemm1_kernel(
    const u16* __restrict__ Abuf, const u16* __restrict__ w2b, u16* __restrict__ Y2,
    const int* __restrict__ ctl) {
    constexpr int NCB = 8;   // 1024 / 128
    constexpr int NK = 32;

    int ntiles = ctl[25];
    int N = ntiles * NCB;
    int bid = blockIdx.x;
    if (bid >= N) return;
    int q = N >> 3, r = N & 7;
    int xcd = bid & 7, seq = bid >> 3;
    int n = (xcd < r ? xcd * (q + 1) : r * (q + 1) + (xcd - r) * q) + seq;
    int e = 0, tstart = 0, tiles_e = 0, m = n;
    for (; e < NEXP; e++) {
        tstart = ctl[280 + e];
        tiles_e = ctl[281 + e] - tstart;
        int sz = tiles_e * NCB;
        if (m < sz) break;
        m -= sz;
    }
    if (e == NEXP) return;
    int cb = m / tiles_e;
    int tt = tstart + (m - cb * tiles_e);
    int rowbase = ctl[112 + tt];
    int segend = ctl[192 + tt];

    __shared__ __align__(16) u16 smem[2 * 128 * 32 * 2];  // 32 KB
    u16* sA = smem;                 // [2][128][32]
    u16* sB = smem + 2 * 128 * 32;  // [2][128][32]

    int tid = threadIdx.x;
    int lane = tid & 63;
    int wv = tid >> 6;
    int wrow = wv >> 1, wcol = wv & 1;
    int lr = lane >> 2;
    int cS = (((lane & 3) ^ ((lane >> 3) & 3)) << 3);
    int l15 = lane & 15, hi = lane >> 4;
    int csr = ((hi ^ ((l15 >> 1) & 3)) << 3);

    u32 rowA[2], rowB[2];
#pragma unroll
    for (int i = 0; i < 2; i++) {
        int slot = rowbase + wv * 32 + i * 16 + lr;
        if (slot >= segend) slot = rowbase;
        rowA[i] = (u32)slot * 1024;
        int rr = cb * 128 + wv * 32 + i * 16 + lr;
        rowB[i] = (u32)e * 1048576 + (u32)rr * 1024;
    }

    f32x4 acc[4][4];
    f32x4 zero = {0.f, 0.f, 0.f, 0.f};
#pragma unroll
    for (int m2 = 0; m2 < 4; m2++)
#pragma unroll
        for (int nn = 0; nn < 4; nn++) acc[m2][nn] = zero;

    auto stage = [&](int buf, int kt) {
        int k0 = kt * 32 + cS;
#pragma unroll
        for (int i = 0; i < 2; i++) {
            gload16(Abuf + rowA[i] + k0, sA + buf * 4096 + (wv * 32 + i * 16) * 32);
            gload16(w2b + rowB[i] + k0, sB + buf * 4096 + (wv * 32 + i * 16) * 32);
        }
    };

    auto compute = [&](int buf) {
        bf16x8 av[4], bv[4];
#pragma unroll
        for (int m2 = 0; m2 < 4; m2++) {
            int rr = wrow * 64 + m2 * 16 + l15;
            av[m2] = *(const bf16x8*)(sA + buf * 4096 + rr * 32 + csr);
        }
#pragma unroll
        for (int nn = 0; nn < 4; nn++) {
            int rr = wcol * 64 + nn * 16 + l15;
            bv[nn] = *(const bf16x8*)(sB + buf * 4096 + rr * 32 + csr);
        }
#pragma unroll
        for (int m2 = 0; m2 < 4; m2++)
#pragma unroll
            for (int nn = 0; nn < 4; nn++)
                acc[m2][nn] = __builtin_amdgcn_mfma_f32_16x16x32_bf16(av[m2], bv[nn], acc[m2][nn], 0, 0, 0);
    };

    stage(0, 0);
    for (int kt = 0; kt < NK; ++kt) {
        __syncthreads();
        if (kt + 1 < NK) stage((kt + 1) & 1, kt + 1);
        compute(kt & 1);
    }

    // Epilogue: plain bf16 stores (each Y2 row owned by exactly one block)
    int colblock = cb * 128 + wcol * 64;
#pragma unroll
    for (int m2 = 0; m2 < 4; m2++) {
        int slotbase = rowbase + wrow * 64 + m2 * 16 + hi * 4;
#pragma unroll
        for (int nn = 0; nn < 4; nn++) {
            int col = colblock + nn * 16 + l15;
#pragma unroll
            for (int j = 0; j < 4; j++) {
                int slot = slotbase + j;
                if (slot < segend)
                    Y2[(size_t)slot * 1024 + col] = f2bf(acc[m2][nn][j]);
            }
        }
    }
}

// ---------------- combine: y[t] = w0*Y2[s0] + w1*Y2[s1]  (Y2 bf16) ----------------------
__global__ __launch_bounds__(256) void combine_kernel(const u16* __restrict__ Y2,
                                                      const int* __restrict__ t2slot,
                                                      const float* __restrict__ t2w,
                                                      float* __restrict__ y) {
    int t = blockIdx.x;
    int d = threadIdx.x * 4;
    int s0 = t2slot[2 * t], s1 = t2slot[2 * t + 1];
    float w0 = t2w[2 * t], w1 = t2w[2 * t + 1];
    uint2 a = *(const uint2*)(Y2 + (size_t)s0 * 1024 + d);
    uint2 b = *(const uint2*)(Y2 + (size_t)s1 * 1024 + d);
    float4 o;
    o.x = w0 * bf2f(a.x & 0xffffu) + w1 * bf2f(b.x & 0xffffu);
    o.y = w0 * bf2f(a.x >> 16)     + w1 * bf2f(b.x >> 16);
    o.z = w0 * bf2f(a.y & 0xffffu) + w1 * bf2f(b.y & 0xffffu);
    o.w = w0 * bf2f(a.y >> 16)     + w1 * bf2f(b.y >> 16);
    *(float4*)(y + (size_t)t * 1024 + d) = o;
}

// ---------------- launch ----------------------------------------------------------------
extern "C" void kernel_launch(void* const* d_in, const int* in_sizes, int n_in,
                              void* d_out, int out_size, void* d_ws, size_t ws_size,
                              hipStream_t stream) {
    const float* x  = (const float*)d_in[0];
    const float* gw = (const float*)d_in[1];
    const float* w1 = (const float*)d_in[2];
    const float* w3 = (const float*)d_in[3];
    const float* w2 = (const float*)d_in[4];
    float* y = (float*)d_out;
    char* ws = (char*)d_ws;

    int*   ctl        = (int*)ws;                    // 4 KB control block
    int*   t2i        = (int*)(ws + 4096);           // 32 KB
    float* t2w        = (float*)(ws + 36864);        // 32 KB
    int*   slot_token = (int*)(ws + 69632);          // 32 KB
    float* slot_wt    = (float*)(ws + 102400);       // 32 KB
    int*   t2slot     = (int*)(ws + 135168);         // 32 KB
    u16*   xb   = (u16*)(ws + 262144);               // 4M elems (8 MB)
    u16*   w1b  = xb  + (size_t)4194304;             // 8M elems each (16 MB)
    u16*   w3b  = w1b + (size_t)8388608;
    u16*   w2b  = w3b + (size_t)8388608;
    u16*   Abuf = w2b + (size_t)8388608;             // 8192 x 1024 bf16
    // Y2 (8192 x 1024 bf16 = 16 MiB) aliases w1b — dead after gemm0.
    u16* Y2 = w1b;

    gate_cvt_kernel<<<1536, 256, 0, stream>>>(x, gw, w1, w3, w2, t2i, t2w, xb, w1b);
    sort_kernel<<<1, 1024, 0, stream>>>(t2i, t2w, ctl, slot_token, slot_wt, t2slot);

    gemm0_kernel<<<MAX_TILES * 16, 256, 0, stream>>>(
        xb, w1b, w3b, Abuf, ctl, slot_token);
    gemm1_kernel<<<MAX_TILES * 8, 256, 0, stream>>>(Abuf, w2b, Y2, ctl);
    combine_kernel<<<NTOK, 256, 0, stream>>>(Y2, t2slot, t2w, y);
}

// Round 11
// 133.706 us; speedup vs baseline: 1.0665x; 1.0665x over previous
//
#include <hip/hip_runtime.h>
#include <hip/hip_bf16.h>

typedef unsigned short u16;
typedef unsigned int u32;
typedef __attribute__((ext_vector_type(8))) short bf16x8;
typedef __attribute__((ext_vector_type(4))) float f32x4;

#define NEXP 8
#define NTOK 4096
#define DDIM 1024
#define MAX_TILES 80

__device__ __forceinline__ u16 f2bf(float f) {
    u32 u = __float_as_uint(f);
    u += 0x7fff + ((u >> 16) & 1);  // RNE
    return (u16)(u >> 16);
}

__device__ __forceinline__ float bf2f(u32 u) { return __uint_as_float(u << 16); }

__device__ __forceinline__ void gload16(const void* g, void* l) {
    __builtin_amdgcn_global_load_lds((const __attribute__((address_space(1))) u32*)g,
                                     (__attribute__((address_space(3))) u32*)l, 16, 0, 0);
}

__device__ __forceinline__ void cvt8(const float* src, u16* dst) {
    float4 a = ((const float4*)src)[0], b = ((const float4*)src)[1];
    uint4 o;
    o.x = (u32)f2bf(a.x) | ((u32)f2bf(a.y) << 16);
    o.y = (u32)f2bf(a.z) | ((u32)f2bf(a.w) << 16);
    o.z = (u32)f2bf(b.x) | ((u32)f2bf(b.y) << 16);
    o.w = (u32)f2bf(b.z) | ((u32)f2bf(b.w) << 16);
    *(uint4*)dst = o;
}

// ---------------- gate (blocks 0..1023) + cvt w1,w3,w2 (blocks 1024..1535) --------------
__global__ __launch_bounds__(256) void gate_cvt_kernel(const float* __restrict__ x,
                                                       const float* __restrict__ gw,
                                                       const float* __restrict__ w1,
                                                       const float* __restrict__ w3,
                                                       const float* __restrict__ w2,
                                                       int* __restrict__ t2i, float* __restrict__ t2w,
                                                       u16* __restrict__ xb, u16* __restrict__ wb) {
    int bid = blockIdx.x;
    int tid = threadIdx.x;
    if (bid >= 1024) {
        // convert w1|w3|w2 -> wb (contiguous bf16), 3.14M chunks of 8 elems
        for (int i = (bid - 1024) * 256 + tid; i < 3145728; i += 131072) {
            const float* src;
            if (i < 1048576)       src = w1 + (size_t)i * 8;
            else if (i < 2097152)  src = w3 + ((size_t)i - 1048576) * 8;
            else                   src = w2 + ((size_t)i - 2097152) * 8;
            cvt8(src, wb + (size_t)i * 8);
        }
        return;
    }
    int wv = tid >> 6, lane = tid & 63;
    int t = bid * 4 + wv;
    const float4* xr = (const float4*)(x + (size_t)t * DDIM);
    float4 xv[4];
#pragma unroll
    for (int q = 0; q < 4; q++) xv[q] = xr[lane * 4 + q];

    uint4 o0, o1;
    o0.x = (u32)f2bf(xv[0].x) | ((u32)f2bf(xv[0].y) << 16);
    o0.y = (u32)f2bf(xv[0].z) | ((u32)f2bf(xv[0].w) << 16);
    o0.z = (u32)f2bf(xv[1].x) | ((u32)f2bf(xv[1].y) << 16);
    o0.w = (u32)f2bf(xv[1].z) | ((u32)f2bf(xv[1].w) << 16);
    o1.x = (u32)f2bf(xv[2].x) | ((u32)f2bf(xv[2].y) << 16);
    o1.y = (u32)f2bf(xv[2].z) | ((u32)f2bf(xv[2].w) << 16);
    o1.z = (u32)f2bf(xv[3].x) | ((u32)f2bf(xv[3].y) << 16);
    o1.w = (u32)f2bf(xv[3].z) | ((u32)f2bf(xv[3].w) << 16);
    uint4* xbo = (uint4*)(xb + (size_t)t * DDIM + lane * 16);
    xbo[0] = o0;
    xbo[1] = o1;

    float acc[NEXP];
#pragma unroll
    for (int e = 0; e < NEXP; e++) acc[e] = 0.f;
#pragma unroll
    for (int e = 0; e < NEXP; e++) {
#pragma unroll
        for (int q = 0; q < 4; q++) {
            float4 g = ((const float4*)gw)[e * 256 + lane * 4 + q];
            acc[e] += xv[q].x * g.x + xv[q].y * g.y + xv[q].z * g.z + xv[q].w * g.w;
        }
    }
#pragma unroll
    for (int e = 0; e < NEXP; e++) {
        float v = acc[e];
#pragma unroll
        for (int off = 32; off; off >>= 1) v += __shfl_xor(v, off, 64);
        acc[e] = v;
    }
    if (lane == 0) {
        float m = acc[0];
#pragma unroll
        for (int e = 1; e < NEXP; e++) m = fmaxf(m, acc[e]);
        float p[NEXP]; float s = 0.f;
#pragma unroll
        for (int e = 0; e < NEXP; e++) { p[e] = __expf(acc[e] - m); s += p[e]; }
        float inv = 1.f / s;
        float best = -1.f, sec = -1.f; int bi = 0, si = 0;
#pragma unroll
        for (int e = 0; e < NEXP; e++) {
            float pe = p[e] * inv;
            if (pe > best) { sec = best; si = bi; best = pe; bi = e; }
            else if (pe > sec) { sec = pe; si = e; }
        }
        t2i[2 * t] = bi;  t2i[2 * t + 1] = si;
        t2w[2 * t] = best; t2w[2 * t + 1] = sec;
    }
}

// ---------------- sort: histogram + block scan + stable counting sort (1 block) --------
// ctl layout (ints): [16..25) slot offsets, [24] total, [25] ntiles,
//   [32..112) tile_expert, [112..192) tile_rowbase, [192..272) tile_segend,
//   [280..289) tilestart prefix (per expert)
__global__ __launch_bounds__(1024) void sort_kernel(const int* __restrict__ t2i,
                                                    const float* __restrict__ t2w,
                                                    int* __restrict__ ctl,
                                                    int* __restrict__ slot_token,
                                                    float* __restrict__ slot_wt,
                                                    int* __restrict__ t2slot) {
    __shared__ int sb[NEXP][1024];  // 32 KB
    __shared__ int wsum[16];
    __shared__ int sex[16];
    __shared__ int stot[NEXP];
    __shared__ int soffs[NEXP + 1];
    int tid = threadIdx.x;
    int lane = tid & 63, wv = tid >> 6;

    int4 a = *(const int4*)(t2i + tid * 8);
    int4 b = *(const int4*)(t2i + tid * 8 + 4);
    int ev0 = a.x, ev1 = a.y, ev2 = a.z, ev3 = a.w;
    int ev4 = b.x, ev5 = b.y, ev6 = b.z, ev7 = b.w;
    u32 cnt = (1u << (ev0 * 4)) + (1u << (ev1 * 4)) + (1u << (ev2 * 4)) + (1u << (ev3 * 4)) +
              (1u << (ev4 * 4)) + (1u << (ev5 * 4)) + (1u << (ev6 * 4)) + (1u << (ev7 * 4));

    for (int e = 0; e < NEXP; e++) {
        int v = (cnt >> (e * 4)) & 15;
        int inc = v;
#pragma unroll
        for (int off = 1; off < 64; off <<= 1) {
            int n = __shfl_up(inc, off, 64);
            if (lane >= off) inc += n;
        }
        if (lane == 63) wsum[wv] = inc;
        __syncthreads();
        if (wv == 0) {
            int w = (lane < 16) ? wsum[lane] : 0;
            int winc = w;
#pragma unroll
            for (int off = 1; off < 16; off <<= 1) {
                int n = __shfl_up(winc, off, 64);
                if (lane >= off) winc += n;
            }
            if (lane < 16) sex[lane] = winc - w;
            if (lane == 15) stot[e] = winc;
        }
        __syncthreads();
        sb[e][tid] = sex[wv] + inc - v;
        __syncthreads();
    }
    if (tid == 0) {
        int o = 0, tt = 0;
        for (int e = 0; e < NEXP; e++) {
            soffs[e] = o;
            ctl[16 + e] = o;
            ctl[280 + e] = tt;  // tilestart prefix
            int n = stot[e];
            for (int r = 0; r < n; r += 128) {
                ctl[32 + tt] = e; ctl[112 + tt] = o + r; ctl[192 + tt] = o + n; tt++;
            }
            o += n;
        }
        soffs[NEXP] = o; ctl[24] = o; ctl[25] = tt; ctl[288] = tt;
    }
    __syncthreads();
#pragma unroll
    for (int j = 0; j < 8; j++) {
        int e;
        switch (j) {
            case 0: e = ev0; break; case 1: e = ev1; break; case 2: e = ev2; break;
            case 3: e = ev3; break; case 4: e = ev4; break; case 5: e = ev5; break;
            case 6: e = ev6; break; default: e = ev7; break;
        }
        int base = sb[e][tid];
        sb[e][tid] = base + 1;
        int slot = soffs[e] + base;
        int p = tid * 8 + j;
        slot_token[slot] = p >> 1;
        slot_wt[slot] = t2w[p];
        t2slot[p] = slot;
    }
}

// ---------------- GEMM0: 128x64 dual-B, BK=32, 32KB LDS, lb(256,4) [VGPR 56 config] -----
// H=Xg@w1^T, G=Xg@w3^T (dual acc), A=silu(H)*G -> Abuf bf16. R4-exact (58us measured).
// NOTE: lb(256,5) squeezes VGPR 56->48 and costs ~10us (R10) — do not raise.
__global__ __launch_bounds__(256, 4) void gemm0_kernel(
    const u16* __restrict__ Amat, const u16* __restrict__ B1g, const u16* __restrict__ B2g,
    u16* __restrict__ OutB,
    const int* __restrict__ ctl, const int* __restrict__ slot_token) {
    constexpr int NB = 2;
    constexpr int NCB = 16;
    constexpr int NK = 32;

    int bid = blockIdx.x;
    int ntiles = ctl[25];
    int N = ntiles * NCB;
    if (bid >= N) return;
    // bijective XCD swizzle (m204)
    int q = N >> 3, r = N & 7;
    int xcd = bid & 7, seq = bid >> 3;
    int n = (xcd < r ? xcd * (q + 1) : r * (q + 1) + (xcd - r) * q) + seq;
    int e = 0, tstart = 0, tiles_e = 0, m = n;
    for (; e < NEXP; e++) {
        tstart = ctl[280 + e];
        tiles_e = ctl[281 + e] - tstart;
        int sz = tiles_e * NCB;
        if (m < sz) break;
        m -= sz;
    }
    if (e == NEXP) return;
    int cb = m / tiles_e;
    int tt = tstart + (m - cb * tiles_e);
    int rowbase = ctl[112 + tt];
    int segend = ctl[192 + tt];

    __shared__ __align__(16) u16 smem[2 * 128 * 32 + 2 * 64 * 32 + 2 * 64 * 32];
    u16* sA = smem;                  // [2][128][32]
    u16* sB1 = smem + 2 * 128 * 32;  // [2][64][32]
    u16* sB2 = sB1 + 2 * 64 * 32;    // [2][64][32]

    int tid = threadIdx.x;
    int lane = tid & 63;
    int wv = tid >> 6;
    int wrow = wv >> 1, wcol = wv & 1;
    int lr = lane >> 2;
    int cS = (((lane & 3) ^ ((lane >> 3) & 3)) << 3);
    int l15 = lane & 15, hi = lane >> 4;
    int csr = ((hi ^ ((l15 >> 1) & 3)) << 3);

    u32 rowA[2];
#pragma unroll
    for (int i = 0; i < 2; i++) {
        int slot = rowbase + wv * 32 + i * 16 + lr;
        if (slot >= segend) slot = rowbase;
        rowA[i] = (u32)slot_token[slot] * 1024;
    }
    u32 rowB0;
    {
        int rr = cb * 64 + wv * 16 + lr;
        rowB0 = (u32)e * 1048576 + (u32)rr * 1024;
    }

    f32x4 accH[4][NB], accG[4][NB];
    f32x4 zero = {0.f, 0.f, 0.f, 0.f};
#pragma unroll
    for (int m2 = 0; m2 < 4; m2++)
#pragma unroll
        for (int nn = 0; nn < NB; nn++) { accH[m2][nn] = zero; accG[m2][nn] = zero; }

    auto stage = [&](int buf, int kt) {
        int k0 = kt * 32 + cS;
        gload16(Amat + rowA[0] + k0, sA + buf * 4096 + (wv * 32) * 32);
        gload16(Amat + rowA[1] + k0, sA + buf * 4096 + (wv * 32 + 16) * 32);
        gload16(B1g + rowB0 + k0, sB1 + buf * 2048 + (wv * 16) * 32);
        gload16(B2g + rowB0 + k0, sB2 + buf * 2048 + (wv * 16) * 32);
    };

    auto compute = [&](int buf) {
        bf16x8 av[4];
#pragma unroll
        for (int m2 = 0; m2 < 4; m2++) {
            int rr = wrow * 64 + m2 * 16 + l15;
            av[m2] = *(const bf16x8*)(sA + buf * 4096 + rr * 32 + csr);
        }
        bf16x8 b1v[NB], b2v[NB];
#pragma unroll
        for (int nn = 0; nn < NB; nn++) {
            int rr = wcol * 32 + nn * 16 + l15;
            b1v[nn] = *(const bf16x8*)(sB1 + buf * 2048 + rr * 32 + csr);
            b2v[nn] = *(const bf16x8*)(sB2 + buf * 2048 + rr * 32 + csr);
        }
#pragma unroll
        for (int m2 = 0; m2 < 4; m2++)
#pragma unroll
            for (int nn = 0; nn < NB; nn++) {
                accH[m2][nn] = __builtin_amdgcn_mfma_f32_16x16x32_bf16(av[m2], b1v[nn], accH[m2][nn], 0, 0, 0);
                accG[m2][nn] = __builtin_amdgcn_mfma_f32_16x16x32_bf16(av[m2], b2v[nn], accG[m2][nn], 0, 0, 0);
            }
    };

    stage(0, 0);
    for (int kt = 0; kt < NK; ++kt) {
        __syncthreads();
        if (kt + 1 < NK) stage((kt + 1) & 1, kt + 1);
        compute(kt & 1);
    }

    int colblock = cb * 64 + wcol * 32;
#pragma unroll
    for (int m2 = 0; m2 < 4; m2++) {
        int slotbase = rowbase + wrow * 64 + m2 * 16 + hi * 4;
#pragma unroll
        for (int nn = 0; nn < NB; nn++) {
            int col = colblock + nn * 16 + l15;
#pragma unroll
            for (int j = 0; j < 4; j++) {
                int slot = slotbase + j;
                if (slot < segend) {
                    float h = accH[m2][nn][j], g = accG[m2][nn][j];
                    float aa = (h / (1.f + __expf(-h))) * g;  // silu(h)*g
                    OutB[(size_t)slot * 1024 + col] = f2bf(aa);
                }
            }
        }
    }
}

// ---------------- GEMM1: Y2[slot] = Abuf @ w2^T (bf16 out, plain stores) ----------------
// 128x128, BK=32, 32KB LDS, 512-block grid (grid-capped at 2/CU).
__global__ __launch_bounds__(256, 4) void gemm1_kernel(
    const u16* __restrict__ Abuf, const u16* __restrict__ w2b, u16* __restrict__ Y2,
    const int* __restrict__ ctl) {
    constexpr int NCB = 8;   // 1024 / 128
    constexpr int NK = 32;

    int ntiles = ctl[25];
    int N = ntiles * NCB;
    int bid = blockIdx.x;
    if (bid >= N) return;
    int q = N >> 3, r = N & 7;
    int xcd = bid & 7, seq = bid >> 3;
    int n = (xcd < r ? xcd * (q + 1) : r * (q + 1) + (xcd - r) * q) + seq;
    int e = 0, tstart = 0, tiles_e = 0, m = n;
    for (; e < NEXP; e++) {
        tstart = ctl[280 + e];
        tiles_e = ctl[281 + e] - tstart;
        int sz = tiles_e * NCB;
        if (m < sz) break;
        m -= sz;
    }
    if (e == NEXP) return;
    int cb = m / tiles_e;
    int tt = tstart + (m - cb * tiles_e);
    int rowbase = ctl[112 + tt];
    int segend = ctl[192 + tt];

    __shared__ __align__(16) u16 smem[2 * 128 * 32 * 2];  // 32 KB
    u16* sA = smem;                 // [2][128][32]
    u16* sB = smem + 2 * 128 * 32;  // [2][128][32]

    int tid = threadIdx.x;
    int lane = tid & 63;
    int wv = tid >> 6;
    int wrow = wv >> 1, wcol = wv & 1;
    int lr = lane >> 2;
    int cS = (((lane & 3) ^ ((lane >> 3) & 3)) << 3);
    int l15 = lane & 15, hi = lane >> 4;
    int csr = ((hi ^ ((l15 >> 1) & 3)) << 3);

    u32 rowA[2], rowB[2];
#pragma unroll
    for (int i = 0; i < 2; i++) {
        int slot = rowbase + wv * 32 + i * 16 + lr;
        if (slot >= segend) slot = rowbase;
        rowA[i] = (u32)slot * 1024;
        int rr = cb * 128 + wv * 32 + i * 16 + lr;
        rowB[i] = (u32)e * 1048576 + (u32)rr * 1024;
    }

    f32x4 acc[4][4];
    f32x4 zero = {0.f, 0.f, 0.f, 0.f};
#pragma unroll
    for (int m2 = 0; m2 < 4; m2++)
#pragma unroll
        for (int nn = 0; nn < 4; nn++) acc[m2][nn] = zero;

    auto stage = [&](int buf, int kt) {
        int k0 = kt * 32 + cS;
#pragma unroll
        for (int i = 0; i < 2; i++) {
            gload16(Abuf + rowA[i] + k0, sA + buf * 4096 + (wv * 32 + i * 16) * 32);
            gload16(w2b + rowB[i] + k0, sB + buf * 4096 + (wv * 32 + i * 16) * 32);
        }
    };

    auto compute = [&](int buf) {
        bf16x8 av[4], bv[4];
#pragma unroll
        for (int m2 = 0; m2 < 4; m2++) {
            int rr = wrow * 64 + m2 * 16 + l15;
            av[m2] = *(const bf16x8*)(sA + buf * 4096 + rr * 32 + csr);
        }
#pragma unroll
        for (int nn = 0; nn < 4; nn++) {
            int rr = wcol * 64 + nn * 16 + l15;
            bv[nn] = *(const bf16x8*)(sB + buf * 4096 + rr * 32 + csr);
        }
#pragma unroll
        for (int m2 = 0; m2 < 4; m2++)
#pragma unroll
            for (int nn = 0; nn < 4; nn++)
                acc[m2][nn] = __builtin_amdgcn_mfma_f32_16x16x32_bf16(av[m2], bv[nn], acc[m2][nn], 0, 0, 0);
    };

    stage(0, 0);
    for (int kt = 0; kt < NK; ++kt) {
        __syncthreads();
        if (kt + 1 < NK) stage((kt + 1) & 1, kt + 1);
        compute(kt & 1);
    }

    // Epilogue: plain bf16 stores (each Y2 row owned by exactly one block)
    int colblock = cb * 128 + wcol * 64;
#pragma unroll
    for (int m2 = 0; m2 < 4; m2++) {
        int slotbase = rowbase + wrow * 64 + m2 * 16 + hi * 4;
#pragma unroll
        for (int nn = 0; nn < 4; nn++) {
            int col = colblock + nn * 16 + l15;
#pragma unroll
            for (int j = 0; j < 4; j++) {
                int slot = slotbase + j;
                if (slot < segend)
                    Y2[(size_t)slot * 1024 + col] = f2bf(acc[m2][nn][j]);
            }
        }
    }
}

// ---------------- combine: y[t] = w0*Y2[s0] + w1*Y2[s1]  (Y2 bf16) ----------------------
__global__ __launch_bounds__(256) void combine_kernel(const u16* __restrict__ Y2,
                                                      const int* __restrict__ t2slot,
                                                      const float* __restrict__ t2w,
                                                      float* __restrict__ y) {
    int t = blockIdx.x;
    int d = threadIdx.x * 4;
    int s0 = t2slot[2 * t], s1 = t2slot[2 * t + 1];
    float w0 = t2w[2 * t], w1 = t2w[2 * t + 1];
    uint2 a = *(const uint2*)(Y2 + (size_t)s0 * 1024 + d);
    uint2 b = *(const uint2*)(Y2 + (size_t)s1 * 1024 + d);
    float4 o;
    o.x = w0 * bf2f(a.x & 0xffffu) + w1 * bf2f(b.x & 0xffffu);
    o.y = w0 * bf2f(a.x >> 16)     + w1 * bf2f(b.x >> 16);
    o.z = w0 * bf2f(a.y & 0xffffu) + w1 * bf2f(b.y & 0xffffu);
    o.w = w0 * bf2f(a.y >> 16)     + w1 * bf2f(b.y >> 16);
    *(float4*)(y + (size_t)t * 1024 + d) = o;
}

// ---------------- launch ----------------------------------------------------------------
extern "C" void kernel_launch(void* const* d_in, const int* in_sizes, int n_in,
                              void* d_out, int out_size, void* d_ws, size_t ws_size,
                              hipStream_t stream) {
    const float* x  = (const float*)d_in[0];
    const float* gw = (const float*)d_in[1];
    const float* w1 = (const float*)d_in[2];
    const float* w3 = (const float*)d_in[3];
    const float* w2 = (const float*)d_in[4];
    float* y = (float*)d_out;
    char* ws = (char*)d_ws;

    int*   ctl        = (int*)ws;                    // 4 KB control block
    int*   t2i        = (int*)(ws + 4096);           // 32 KB
    float* t2w        = (float*)(ws + 36864);        // 32 KB
    int*   slot_token = (int*)(ws + 69632);          // 32 KB
    float* slot_wt    = (float*)(ws + 102400);       // 32 KB
    int*   t2slot     = (int*)(ws + 135168);         // 32 KB
    u16*   xb   = (u16*)(ws + 262144);               // 4M elems (8 MB)
    u16*   w1b  = xb  + (size_t)4194304;             // 8M elems each (16 MB)
    u16*   w3b  = w1b + (size_t)8388608;
    u16*   w2b  = w3b + (size_t)8388608;
    u16*   Abuf = w2b + (size_t)8388608;             // 8192 x 1024 bf16
    // Y2 (8192 x 1024 bf16 = 16 MiB) aliases w1b — dead after gemm0.
    u16* Y2 = w1b;

    gate_cvt_kernel<<<1536, 256, 0, stream>>>(x, gw, w1, w3, w2, t2i, t2w, xb, w1b);
    sort_kernel<<<1, 1024, 0, stream>>>(t2i, t2w, ctl, slot_token, slot_wt, t2slot);

    gemm0_kernel<<<MAX_TILES * 16, 256, 0, stream>>>(
        xb, w1b, w3b, Abuf, ctl, slot_token);
    gemm1_kernel<<<MAX_TILES * 8, 256, 0, stream>>>(Abuf, w2b, Y2, ctl);
    combine_kernel<<<NTOK, 256, 0, stream>>>(Y2, t2slot, t2w, y);
}